// Round 1
// baseline (47281.262 us; speedup 1.0000x reference)
//
#include <hip/hip_runtime.h>
#include <hip/hip_bf16.h>
#include <hip/hip_cooperative_groups.h>

namespace cg = cooperative_groups;

typedef __attribute__((ext_vector_type(8))) short short8;
typedef __attribute__((ext_vector_type(4))) float f32x4;
typedef unsigned int u32;
typedef unsigned short u16;

#define T_STEPS 512
#define B_SZ    128
#define I_SZ    512
#define U_SZ    1024
#define K_TOT   1536   // 512 x-part + 1024 h-part

// ws layout (bytes)
#define XB_OFF   0            // 33,554,432 bf16 = 67,108,864 B   (X as bf16, [B][T][I])
#define WC_OFF   67108864     // 4096*1536 bf16 = 12,582,912 B    (W packed [gcol][k]: k<512 = W_ih, else W_hh)
#define BIAS_OFF 79691776     // 4096 f32 = 16,384 B              (b_ih + b_hh)
#define HBUF_OFF 79708160     // 2*128*1024 bf16 = 524,288 B      (double-buffered h)
// total 80,232,448 B

__device__ __forceinline__ u16 f2bf(float f) {
  u32 u = __float_as_uint(f);
  u32 r = (u + 0x7fffu + ((u >> 16) & 1u)) >> 16;   // RNE; inputs finite
  return (u16)r;
}

__device__ __forceinline__ float sigm(float x) { return 1.f / (1.f + __expf(-x)); }
__device__ __forceinline__ float tanh_s(float x) {
  float ax = fabsf(x);
  float e  = __expf(-2.f * ax);          // in (0,1], no overflow
  float t  = (1.f - e) / (1.f + e);
  return copysignf(t, x);
}

// ---- prep kernels ---------------------------------------------------------
__global__ void k_convX(const float* __restrict__ X, u16* __restrict__ Xb) {
  u32 i = blockIdx.x * 256u + threadIdx.x;            // grid covers 8,388,608 exactly
  float4 v = reinterpret_cast<const float4*>(X)[i];
  uint2 o;
  o.x = (u32)f2bf(v.x) | ((u32)f2bf(v.y) << 16);
  o.y = (u32)f2bf(v.z) | ((u32)f2bf(v.w) << 16);
  reinterpret_cast<uint2*>(Xb)[i] = o;
}

__global__ void k_packW(const float* __restrict__ Wih, const float* __restrict__ Whh,
                        u16* __restrict__ Wc) {
  const int gcol = blockIdx.x;                        // 4096 rows
  for (int k = threadIdx.x; k < K_TOT; k += 256) {
    float v = (k < I_SZ) ? Wih[(size_t)gcol * I_SZ + k]
                         : Whh[(size_t)gcol * U_SZ + (k - I_SZ)];
    Wc[(size_t)gcol * K_TOT + k] = f2bf(v);
  }
}

__global__ void k_misc(const float* __restrict__ bih, const float* __restrict__ bhh,
                       float* __restrict__ bias, u32* __restrict__ hz) {
  u32 i = blockIdx.x * 256u + threadIdx.x;            // grid covers 131,072 exactly
  if (i < 4096u) bias[i] = bih[i] + bhh[i];
  hz[i] = 0u;                                         // zero both h buffers (524,288 B)
}

// ---- persistent cooperative scan ------------------------------------------
// 256 WGs x 512 thr. Cluster cl = wg>>7 (2 clusters x 64 batch rows).
// wloc = wg&127 -> units u0 = wloc*8 (8 units => 32 gate cols: local col = gate*8+du).
// Waves: wid = tid>>6: rg = wid>>2 (2 row-groups of 32), kh = wid&3 (4-way K split, 384 each).
// Per wave: 2 row-tiles x 2 col-tiles, 12 k-iters of 32 => 48 MFMAs; B-frags persistent (96 VGPR).
__global__ __launch_bounds__(512, 2)
void lstm_scan(const u16* __restrict__ Xb, const u16* __restrict__ Wc,
               const float* __restrict__ bias, u16* __restrict__ hbuf,
               float* __restrict__ out) {
  __shared__ float gbuf[4][64][33];                   // [kh][row][col(+pad)] = 33,792 B

  const int tid  = threadIdx.x;
  const int wg   = blockIdx.x;
  const int cl   = wg >> 7;
  const int wloc = wg & 127;
  const int rb   = cl * 64;                           // batch row base of cluster
  const int u0   = wloc * 8;                          // unit base of this WG
  const int wid  = tid >> 6;
  const int lane = tid & 63;
  const int l15  = lane & 15;
  const int kg   = lane >> 4;                         // 0..3 (k sub-chunk of 8)
  const int rg   = wid >> 2;                          // 0..1 row group
  const int kh   = wid & 3;                           // 0..3 K split

  // --- persistent B fragments (W slice) in VGPRs ---
  short8 Bf[12][2];
  #pragma unroll
  for (int ct = 0; ct < 2; ++ct) {
    const int lc   = ct * 16 + l15;                   // local col 0..31
    const int gcol = (lc >> 3) * 1024 + u0 + (lc & 7);
    const u16* wrow = Wc + (size_t)gcol * K_TOT;
    #pragma unroll
    for (int i = 0; i < 12; ++i) {
      const int k = kh * 384 + i * 32 + kg * 8;
      Bf[i][ct] = *reinterpret_cast<const short8*>(wrow + k);
    }
  }

  // --- update-phase constants: thread owns cell (b = rb+b_l, u = u0+du) ---
  const int b_l = tid >> 3;                           // 0..63
  const int du  = tid & 7;                            // 0..7
  float bsum[4];
  #pragma unroll
  for (int g = 0; g < 4; ++g) bsum[g] = bias[g * 1024 + u0 + du];
  float c_state = 0.f;
  float* orow = out + (size_t)(rb + b_l) * (T_STEPS * U_SZ) + u0 + du;
  const int hidx = (rb + b_l) * U_SZ + u0 + du;

  // --- A-operand row pointers ---
  const int r0 = rb + rg * 32 + l15;                  // row-tile 0
  const int r1 = r0 + 16;                             // row-tile 1
  const u16* xrow0 = Xb + (size_t)r0 * (T_STEPS * I_SZ);
  const u16* xrow1 = Xb + (size_t)r1 * (T_STEPS * I_SZ);

  cg::grid_group grid = cg::this_grid();

  for (int t = 0; t < T_STEPS; ++t) {
    const u16* hsrc = hbuf + ((t & 1) ^ 1) * (B_SZ * U_SZ);
    u16*       hdst = hbuf + (t & 1) * (B_SZ * U_SZ);

    const u16* px0 = xrow0 + (size_t)t * I_SZ;
    const u16* px1 = xrow1 + (size_t)t * I_SZ;
    const u16* ph0 = hsrc + (size_t)r0 * U_SZ;
    const u16* ph1 = hsrc + (size_t)r1 * U_SZ;

    f32x4 acc[2][2];
    #pragma unroll
    for (int rt = 0; rt < 2; ++rt)
      #pragma unroll
      for (int ct = 0; ct < 2; ++ct)
        acc[rt][ct] = (f32x4){0.f, 0.f, 0.f, 0.f};

    #pragma unroll
    for (int i = 0; i < 12; ++i) {
      const int k = kh * 384 + i * 32 + kg * 8;       // region is uniform per i (boundary 512 ≡ 0 mod 32)
      const u16* p0;
      const u16* p1;
      if (k < I_SZ) { p0 = px0 + k;          p1 = px1 + k; }
      else          { p0 = ph0 + (k - I_SZ); p1 = ph1 + (k - I_SZ); }
      const short8 a0 = *reinterpret_cast<const short8*>(p0);
      const short8 a1 = *reinterpret_cast<const short8*>(p1);
      #pragma unroll
      for (int ct = 0; ct < 2; ++ct) {
        acc[0][ct] = __builtin_amdgcn_mfma_f32_16x16x32_bf16(a0, Bf[i][ct], acc[0][ct], 0, 0, 0);
        acc[1][ct] = __builtin_amdgcn_mfma_f32_16x16x32_bf16(a1, Bf[i][ct], acc[1][ct], 0, 0, 0);
      }
    }

    // partial sums -> LDS. C/D layout: col = lane&15, row = (lane>>4)*4 + j
    #pragma unroll
    for (int rt = 0; rt < 2; ++rt)
      #pragma unroll
      for (int ct = 0; ct < 2; ++ct)
        #pragma unroll
        for (int j = 0; j < 4; ++j)
          gbuf[kh][rg * 32 + rt * 16 + kg * 4 + j][ct * 16 + l15] = acc[rt][ct][j];
    __syncthreads();

    // cell update: one (b,u) per thread
    float gs[4];
    #pragma unroll
    for (int g = 0; g < 4; ++g) {
      float s = bsum[g];
      #pragma unroll
      for (int k2 = 0; k2 < 4; ++k2) s += gbuf[k2][b_l][g * 8 + du];
      gs[g] = s;
    }
    const float ig = sigm(gs[0]);
    const float fg = sigm(gs[1]);
    const float gg = tanh_s(gs[2]);
    const float og = sigm(gs[3]);
    c_state = fg * c_state + ig * gg;
    const float h = og * tanh_s(c_state);

    orow[(size_t)t * U_SZ] = h;                       // fp32 output [B][T][U]
    hdst[hidx] = f2bf(h);                             // bf16 h for next step

    __threadfence();
    grid.sync();                                      // also fences gbuf reuse
  }
}

// ---- launch ---------------------------------------------------------------
extern "C" void kernel_launch(void* const* d_in, const int* in_sizes, int n_in,
                              void* d_out, int out_size, void* d_ws, size_t ws_size,
                              hipStream_t stream) {
  const float* X   = (const float*)d_in[0];
  const float* Wih = (const float*)d_in[1];
  const float* Whh = (const float*)d_in[2];
  const float* bih = (const float*)d_in[3];
  const float* bhh = (const float*)d_in[4];
  float* out = (float*)d_out;
  char*  ws  = (char*)d_ws;

  u16*   Xb   = (u16*)(ws + XB_OFF);
  u16*   Wc   = (u16*)(ws + WC_OFF);
  float* bias = (float*)(ws + BIAS_OFF);
  u16*   hbuf = (u16*)(ws + HBUF_OFF);

  hipLaunchKernelGGL(k_convX, dim3(32768), dim3(256), 0, stream, X, Xb);
  hipLaunchKernelGGL(k_packW, dim3(4096), dim3(256), 0, stream, Wih, Whh, Wc);
  hipLaunchKernelGGL(k_misc,  dim3(512),  dim3(256), 0, stream, bih, bhh, bias, (u32*)hbuf);

  void* args[] = {(void*)&Xb, (void*)&Wc, (void*)&bias, (void*)&hbuf, (void*)&out};
  hipLaunchCooperativeKernel((void*)lstm_scan, dim3(256), dim3(512), args, 0, stream);
}

// Round 2
// 7704.785 us; speedup vs baseline: 6.1366x; 6.1366x over previous
//
#include <hip/hip_runtime.h>
#include <hip/hip_bf16.h>

typedef __attribute__((ext_vector_type(8))) short short8;
typedef __attribute__((ext_vector_type(4))) float f32x4;
typedef unsigned int u32;
typedef unsigned short u16;

#define T_STEPS 512
#define B_SZ    128
#define I_SZ    512
#define U_SZ    1024
#define K_TOT   1536   // 512 x-part + 1024 h-part

// ws layout (bytes)
#define XB_OFF   0            // 33,554,432 bf16 = 67,108,864 B   (X as bf16, [B][T][I])
#define WC_OFF   67108864     // 4096*1536 bf16 = 12,582,912 B    (W packed [gcol][k])
#define FLAG_OFF 79691776     // 256 u32 = 1,024 B                (per-WG step flags)
#define HBUF_OFF 79708160     // 2*128*1024 bf16 = 524,288 B      (double-buffered h)
// total 80,232,448 B (same as round 1)

__device__ __forceinline__ u16 f2bf(float f) {
  u32 u = __float_as_uint(f);
  u32 r = (u + 0x7fffu + ((u >> 16) & 1u)) >> 16;   // RNE; inputs finite
  return (u16)r;
}

__device__ __forceinline__ float sigm(float x) { return 1.f / (1.f + __expf(-x)); }
__device__ __forceinline__ float tanh_s(float x) {
  float ax = fabsf(x);
  float e  = __expf(-2.f * ax);          // in (0,1], no overflow
  float t  = (1.f - e) / (1.f + e);
  return copysignf(t, x);
}

// ---- prep kernels ---------------------------------------------------------
__global__ void k_convX(const float* __restrict__ X, u16* __restrict__ Xb) {
  u32 i = blockIdx.x * 256u + threadIdx.x;            // grid covers 8,388,608 exactly
  float4 v = reinterpret_cast<const float4*>(X)[i];
  uint2 o;
  o.x = (u32)f2bf(v.x) | ((u32)f2bf(v.y) << 16);
  o.y = (u32)f2bf(v.z) | ((u32)f2bf(v.w) << 16);
  reinterpret_cast<uint2*>(Xb)[i] = o;
}

__global__ void k_packW(const float* __restrict__ Wih, const float* __restrict__ Whh,
                        u16* __restrict__ Wc) {
  const int gcol = blockIdx.x;                        // 4096 rows
  for (int k = threadIdx.x; k < K_TOT; k += 256) {
    float v = (k < I_SZ) ? Wih[(size_t)gcol * I_SZ + k]
                         : Whh[(size_t)gcol * U_SZ + (k - I_SZ)];
    Wc[(size_t)gcol * K_TOT + k] = f2bf(v);
  }
}

__global__ void k_zero(u32* __restrict__ hz, u32* __restrict__ flags) {
  u32 i = blockIdx.x * 256u + threadIdx.x;            // 513 blocks -> 131,328 threads
  if (i < 131072u) hz[i] = 0u;                        // both h buffers (524,288 B)
  else             flags[i - 131072u] = 0u;           // 256 flags
}

// ---- custom grid barrier pieces -------------------------------------------
__device__ __forceinline__ void poll_flags(const u32* flags, u32 tgt, int lane) {
  for (;;) {
    u32 a = __hip_atomic_load(flags + lane,       __ATOMIC_RELAXED, __HIP_MEMORY_SCOPE_AGENT);
    u32 b = __hip_atomic_load(flags + lane + 64,  __ATOMIC_RELAXED, __HIP_MEMORY_SCOPE_AGENT);
    u32 c = __hip_atomic_load(flags + lane + 128, __ATOMIC_RELAXED, __HIP_MEMORY_SCOPE_AGENT);
    u32 d = __hip_atomic_load(flags + lane + 192, __ATOMIC_RELAXED, __HIP_MEMORY_SCOPE_AGENT);
    bool ok = (a >= tgt) & (b >= tgt) & (c >= tgt) & (d >= tgt);
    if (__all((int)ok)) return;
    __builtin_amdgcn_s_sleep(1);
  }
}

// ---- persistent cooperative scan ------------------------------------------
// 256 WGs x 512 thr. Cluster cl = wg>>7 (2 clusters x 64 batch rows).
// wloc = wg&127 -> units u0 = wloc*8 (32 gate cols: local col = gate*8+du).
// Waves: rg = wid>>2 (2 row-groups of 32), kh = wid&3.
// K mapping (interleaved so every wave has 4 x-iters + 8 h-iters):
//   iter i, wave kh: k = (i*4 + kh)*32 + kg*8;  i<4 -> x (k<512), i>=4 -> h.
__global__ __launch_bounds__(512, 2)
void lstm_scan(const u16* __restrict__ Xb, const u16* __restrict__ Wc,
               const float* __restrict__ bih, const float* __restrict__ bhh,
               u16* __restrict__ hbuf, u32* __restrict__ flags,
               float* __restrict__ out) {
  __shared__ float gbuf[4][64][36];                   // stride 36: 2-way-max banks

  const int tid  = threadIdx.x;
  const int wg   = blockIdx.x;
  const int cl   = wg >> 7;
  const int wloc = wg & 127;
  const int rb   = cl * 64;
  const int u0   = wloc * 8;
  const int wid  = tid >> 6;
  const int lane = tid & 63;
  const int l15  = lane & 15;
  const int kg   = lane >> 4;
  const int rg   = wid >> 2;
  const int kh   = wid & 3;

  // --- persistent B fragments (W slice) in VGPRs ---
  short8 Bf[12][2];
  #pragma unroll
  for (int ct = 0; ct < 2; ++ct) {
    const int lc   = ct * 16 + l15;
    const int gcol = (lc >> 3) * 1024 + u0 + (lc & 7);
    const u16* wrow = Wc + (size_t)gcol * K_TOT;
    #pragma unroll
    for (int i = 0; i < 12; ++i) {
      const int k = (i * 4 + kh) * 32 + kg * 8;
      Bf[i][ct] = *reinterpret_cast<const short8*>(wrow + k);
    }
  }

  // --- update-phase constants ---
  const int b_l = tid >> 3;
  const int du  = tid & 7;
  float bsum[4];
  #pragma unroll
  for (int g = 0; g < 4; ++g)
    bsum[g] = bih[g * 1024 + u0 + du] + bhh[g * 1024 + u0 + du];
  float c_state = 0.f;
  float* orow = out + (size_t)(rb + b_l) * (T_STEPS * U_SZ) + u0 + du;
  const int hidx = (rb + b_l) * U_SZ + u0 + du;

  // --- A-operand row pointers ---
  const int r0 = rb + rg * 32 + l15;
  const int r1 = r0 + 16;
  const u16* xrow0 = Xb + (size_t)r0 * (T_STEPS * I_SZ);
  const u16* xrow1 = Xb + (size_t)r1 * (T_STEPS * I_SZ);

  for (int t = 0; t < T_STEPS; ++t) {
    const u16* hsrc = hbuf + ((t & 1) ^ 1) * (B_SZ * U_SZ);
    u16*       hdst = hbuf + (t & 1) * (B_SZ * U_SZ);
    const u16* px0 = xrow0 + (size_t)t * I_SZ;
    const u16* px1 = xrow1 + (size_t)t * I_SZ;
    const u16* ph0 = hsrc + (size_t)r0 * U_SZ;
    const u16* ph1 = hsrc + (size_t)r1 * U_SZ;

    f32x4 acc[2][2];
    #pragma unroll
    for (int rt = 0; rt < 2; ++rt)
      #pragma unroll
      for (int ct = 0; ct < 2; ++ct)
        acc[rt][ct] = (f32x4){0.f, 0.f, 0.f, 0.f};

    // ---- x-phase: no dependence on h_{t-1}; overlaps barrier latency ----
    #pragma unroll
    for (int i = 0; i < 4; ++i) {
      const int k = (i * 4 + kh) * 32 + kg * 8;
      const short8 a0 = *reinterpret_cast<const short8*>(px0 + k);
      const short8 a1 = *reinterpret_cast<const short8*>(px1 + k);
      #pragma unroll
      for (int ct = 0; ct < 2; ++ct) {
        acc[0][ct] = __builtin_amdgcn_mfma_f32_16x16x32_bf16(a0, Bf[i][ct], acc[0][ct], 0, 0, 0);
        acc[1][ct] = __builtin_amdgcn_mfma_f32_16x16x32_bf16(a1, Bf[i][ct], acc[1][ct], 0, 0, 0);
      }
    }

    // ---- wait: h_{t-1} ready (flags >= t). t=0 passes immediately ----
    if (tid < 64) poll_flags(flags, (u32)t, lane);
    __syncthreads();
    if (tid == 0) __builtin_amdgcn_fence(__ATOMIC_ACQUIRE, "agent");  // one buffer_inv/CU
    __syncthreads();

    // ---- h-phase ----
    #pragma unroll
    for (int i = 4; i < 12; ++i) {
      const int k = (i * 4 + kh) * 32 + kg * 8 - 512;
      const short8 a0 = *reinterpret_cast<const short8*>(ph0 + k);
      const short8 a1 = *reinterpret_cast<const short8*>(ph1 + k);
      #pragma unroll
      for (int ct = 0; ct < 2; ++ct) {
        acc[0][ct] = __builtin_amdgcn_mfma_f32_16x16x32_bf16(a0, Bf[i][ct], acc[0][ct], 0, 0, 0);
        acc[1][ct] = __builtin_amdgcn_mfma_f32_16x16x32_bf16(a1, Bf[i][ct], acc[1][ct], 0, 0, 0);
      }
    }

    // ---- reduce partials via LDS. C/D: col = lane&15, row = (lane>>4)*4 + j ----
    #pragma unroll
    for (int rt = 0; rt < 2; ++rt)
      #pragma unroll
      for (int ct = 0; ct < 2; ++ct)
        #pragma unroll
        for (int j = 0; j < 4; ++j)
          gbuf[kh][rg * 32 + rt * 16 + kg * 4 + j][ct * 16 + l15] = acc[rt][ct][j];
    __syncthreads();

    // ---- cell update: one (b,u) per thread ----
    float gs[4];
    #pragma unroll
    for (int g = 0; g < 4; ++g) {
      float s = bsum[g];
      #pragma unroll
      for (int k2 = 0; k2 < 4; ++k2) s += gbuf[k2][b_l][g * 8 + du];
      gs[g] = s;
    }
    const float ig = sigm(gs[0]);
    const float fg = sigm(gs[1]);
    const float gg = tanh_s(gs[2]);
    const float og = sigm(gs[3]);
    c_state = fg * c_state + ig * gg;
    const float h = og * tanh_s(c_state);

    orow[(size_t)t * U_SZ] = h;                       // fp32 output
    hdst[hidx] = f2bf(h);                             // bf16 h for next step

    // ---- publish: drain stores (implicit vmcnt(0) at barrier), release, flag ----
    __syncthreads();                                  // also: gbuf reads done (WAR safe)
    if (tid == 0) {
      __builtin_amdgcn_fence(__ATOMIC_RELEASE, "agent");   // one buffer_wbl2/CU
      __hip_atomic_store(flags + wg, (u32)(t + 1), __ATOMIC_RELAXED, __HIP_MEMORY_SCOPE_AGENT);
    }
  }
}

// ---- launch ---------------------------------------------------------------
extern "C" void kernel_launch(void* const* d_in, const int* in_sizes, int n_in,
                              void* d_out, int out_size, void* d_ws, size_t ws_size,
                              hipStream_t stream) {
  const float* X   = (const float*)d_in[0];
  const float* Wih = (const float*)d_in[1];
  const float* Whh = (const float*)d_in[2];
  const float* bih = (const float*)d_in[3];
  const float* bhh = (const float*)d_in[4];
  float* out = (float*)d_out;
  char*  ws  = (char*)d_ws;

  u16* Xb    = (u16*)(ws + XB_OFF);
  u16* Wc    = (u16*)(ws + WC_OFF);
  u32* flags = (u32*)(ws + FLAG_OFF);
  u16* hbuf  = (u16*)(ws + HBUF_OFF);

  hipLaunchKernelGGL(k_convX, dim3(32768), dim3(256), 0, stream, X, Xb);
  hipLaunchKernelGGL(k_packW, dim3(4096), dim3(256), 0, stream, Wih, Whh, Wc);
  hipLaunchKernelGGL(k_zero,  dim3(513),  dim3(256), 0, stream, (u32*)hbuf, flags);

  void* args[] = {(void*)&Xb, (void*)&Wc, (void*)&bih, (void*)&bhh,
                  (void*)&hbuf, (void*)&flags, (void*)&out};
  hipLaunchCooperativeKernel((void*)lstm_scan, dim3(256), dim3(512), args, 0, stream);
}

// Round 3
// 2605.479 us; speedup vs baseline: 18.1469x; 2.9571x over previous
//
#include <hip/hip_runtime.h>
#include <hip/hip_bf16.h>

typedef __attribute__((ext_vector_type(8))) short short8;
typedef __attribute__((ext_vector_type(4))) float f32x4;
typedef unsigned int u32;
typedef unsigned short u16;

#define T_STEPS 512
#define B_SZ    128
#define I_SZ    512
#define U_SZ    1024
#define K_TOT   1536   // 512 x-part + 1024 h-part

// ws layout (bytes)
#define XB_OFF   0            // X as bf16 [B][T][I] = 67,108,864 B
#define WC_OFF   67108864     // W packed [gcol][k] bf16 = 12,582,912 B
#define FLAG_OFF 79691776     // 256 u32 flags
#define HBUF_OFF 79708160     // 2 x 128 x 1024 bf16 (double-buffered h)
// total 80,232,448 B

__device__ __forceinline__ u16 f2bf(float f) {
  u32 u = __float_as_uint(f);
  u32 r = (u + 0x7fffu + ((u >> 16) & 1u)) >> 16;   // RNE; inputs finite
  return (u16)r;
}

__device__ __forceinline__ float sigm(float x) { return 1.f / (1.f + __expf(-x)); }
__device__ __forceinline__ float tanh_s(float x) {
  float ax = fabsf(x);
  float e  = __expf(-2.f * ax);
  float t  = (1.f - e) / (1.f + e);
  return copysignf(t, x);
}

// ---- prep kernels ---------------------------------------------------------
__global__ void k_convX(const float* __restrict__ X, u16* __restrict__ Xb) {
  u32 i = blockIdx.x * 256u + threadIdx.x;            // covers 8,388,608 exactly
  float4 v = reinterpret_cast<const float4*>(X)[i];
  uint2 o;
  o.x = (u32)f2bf(v.x) | ((u32)f2bf(v.y) << 16);
  o.y = (u32)f2bf(v.z) | ((u32)f2bf(v.w) << 16);
  reinterpret_cast<uint2*>(Xb)[i] = o;
}

__global__ void k_packW(const float* __restrict__ Wih, const float* __restrict__ Whh,
                        u16* __restrict__ Wc) {
  const int gcol = blockIdx.x;                        // 4096 rows
  for (int k = threadIdx.x; k < K_TOT; k += 256) {
    float v = (k < I_SZ) ? Wih[(size_t)gcol * I_SZ + k]
                         : Whh[(size_t)gcol * U_SZ + (k - I_SZ)];
    Wc[(size_t)gcol * K_TOT + k] = f2bf(v);
  }
}

__global__ void k_zero(u32* __restrict__ hz, u32* __restrict__ flags) {
  u32 i = blockIdx.x * 256u + threadIdx.x;            // 513 blocks
  if (i < 131072u) hz[i] = 0u;                        // both h buffers
  else             flags[i - 131072u] = 0u;           // 256 flags
}

// ---- cache-bypass (L1+L2) primitives: h goes straight to/from L3 ----------
__device__ __forceinline__ short8 load_b128_bypass(const u16* p) {
  short8 r;
  asm volatile("global_load_dwordx4 %0, %1, off sc0 sc1" : "=v"(r) : "v"(p));
  return r;   // NOT ready until explicit s_waitcnt vmcnt(0)
}
__device__ __forceinline__ void store_b16_bypass(u16* p, u32 v) {
  asm volatile("global_store_short %0, %1, off sc0 sc1" :: "v"(p), "v"(v));
}

__device__ __forceinline__ void poll_flags(const u32* flags, u32 tgt, int lane) {
  for (;;) {
    u32 a = __hip_atomic_load(flags + lane,       __ATOMIC_RELAXED, __HIP_MEMORY_SCOPE_AGENT);
    u32 b = __hip_atomic_load(flags + lane + 64,  __ATOMIC_RELAXED, __HIP_MEMORY_SCOPE_AGENT);
    u32 c = __hip_atomic_load(flags + lane + 128, __ATOMIC_RELAXED, __HIP_MEMORY_SCOPE_AGENT);
    u32 d = __hip_atomic_load(flags + lane + 192, __ATOMIC_RELAXED, __HIP_MEMORY_SCOPE_AGENT);
    bool ok = (a >= tgt) & (b >= tgt) & (c >= tgt) & (d >= tgt);
    if (__all((int)ok)) return;
    __builtin_amdgcn_s_sleep(1);
  }
}

// ---- persistent scan ------------------------------------------------------
// 256 WGs x 512 thr. cluster cl = wg>>6 (4 clusters x 32 batch rows).
// wloc = wg&63 -> u0 = wloc*16 (64 gate cols = 4 gates x 16 units).
// 8 waves = 8-way K split (kw = wid, 192 K each, ALL 64 cols): no A duplication.
// Per wave: 2 row-tiles x 4 col-tiles x 6 k-iters(32) = 48 MFMAs; Bf = 96 VGPR.
// K map: iter i (0..5): k = (i*8+kw)*32 + kg*8; i<2 -> x-part, i>=2 -> h-part.
__global__ __launch_bounds__(512, 2)
void lstm_scan(const u16* __restrict__ Xb, const u16* __restrict__ Wc,
               const float* __restrict__ bih, const float* __restrict__ bhh,
               u16* __restrict__ hbuf, u32* __restrict__ flags,
               float* __restrict__ out) {
  // [kw][col64][row32+4pad]: b128 writes; reads (4*uu + b_l) are conflict-free
  __shared__ __align__(16) float gbuf[8][64][36];     // 73,728 B

  const int tid  = threadIdx.x;
  const int wg   = blockIdx.x;
  const int cl   = wg >> 6;
  const int wloc = wg & 63;
  const int rb   = cl * 32;                           // batch row base
  const int u0   = wloc * 16;                         // unit base
  const int wid  = tid >> 6;
  const int lane = tid & 63;
  const int l15  = lane & 15;
  const int kg   = lane >> 4;                         // k sub-chunk of 8
  const int kw   = wid;                               // 8-way K split

  // --- persistent B fragments (W slice) in VGPRs: Bf[6][4] = 96 regs ---
  short8 Bf[6][4];
  #pragma unroll
  for (int ct = 0; ct < 4; ++ct) {
    const int gcol = ct * 1024 + u0 + l15;            // gate=ct, unit=u0+l15
    const u16* wrow = Wc + (size_t)gcol * K_TOT;
    #pragma unroll
    for (int i = 0; i < 6; ++i) {
      const int k = (i * 8 + kw) * 32 + kg * 8;
      Bf[i][ct] = *reinterpret_cast<const short8*>(wrow + k);
    }
  }

  // --- cell ownership: thread -> (row rb+b_l, unit u0+uu) ---
  const int b_l = tid >> 4;                           // 0..31
  const int uu  = tid & 15;                           // 0..15
  float bsum[4];
  #pragma unroll
  for (int g = 0; g < 4; ++g)
    bsum[g] = bih[g * 1024 + u0 + uu] + bhh[g * 1024 + u0 + uu];
  float c_state = 0.f;
  float* orow = out + (size_t)(rb + b_l) * (T_STEPS * U_SZ) + u0 + uu;
  const int hidx = (rb + b_l) * U_SZ + u0 + uu;

  // --- A-operand rows (per wave: 2 row-tiles) ---
  const int r0 = rb + l15;                            // row-tile 0
  const int r1 = r0 + 16;                             // row-tile 1
  const u16* xrow0 = Xb + (size_t)r0 * (T_STEPS * I_SZ);
  const u16* xrow1 = Xb + (size_t)r1 * (T_STEPS * I_SZ);

  for (int t = 0; t < T_STEPS; ++t) {
    const u16* hsrc = hbuf + ((t & 1) ^ 1) * (B_SZ * U_SZ);
    u16*       hdst = hbuf + (t & 1) * (B_SZ * U_SZ);
    const u16* px0 = xrow0 + (size_t)t * I_SZ;
    const u16* px1 = xrow1 + (size_t)t * I_SZ;

    f32x4 acc[2][4];
    #pragma unroll
    for (int rt = 0; rt < 2; ++rt)
      #pragma unroll
      for (int ct = 0; ct < 4; ++ct)
        acc[rt][ct] = (f32x4){0.f, 0.f, 0.f, 0.f};

    // ---- x-phase (plain cached loads; L2 stays hot — no fences anywhere) ----
    #pragma unroll
    for (int i = 0; i < 2; ++i) {
      const int k = (i * 8 + kw) * 32 + kg * 8;       // 0..511
      const short8 a0 = *reinterpret_cast<const short8*>(px0 + k);
      const short8 a1 = *reinterpret_cast<const short8*>(px1 + k);
      #pragma unroll
      for (int ct = 0; ct < 4; ++ct) {
        acc[0][ct] = __builtin_amdgcn_mfma_f32_16x16x32_bf16(a0, Bf[i][ct], acc[0][ct], 0, 0, 0);
        acc[1][ct] = __builtin_amdgcn_mfma_f32_16x16x32_bf16(a1, Bf[i][ct], acc[1][ct], 0, 0, 0);
      }
    }

    // ---- wait for h_{t-1} (flags >= t; t=0 passes) ----
    if (tid < 64) poll_flags(flags, (u32)t, lane);
    __syncthreads();

    // ---- h-phase: batch all 8 bypass loads, one drain, then MFMA ----
    short8 hA[4][2];
    #pragma unroll
    for (int ih = 0; ih < 4; ++ih) {
      const int ku = (ih * 8 + kw) * 32 + kg * 8;     // 0..1023
      hA[ih][0] = load_b128_bypass(hsrc + (size_t)r0 * U_SZ + ku);
      hA[ih][1] = load_b128_bypass(hsrc + (size_t)r1 * U_SZ + ku);
    }
    asm volatile("s_waitcnt vmcnt(0)" ::: "memory");
    __builtin_amdgcn_sched_barrier(0);                // keep MFMAs below the wait
    #pragma unroll
    for (int ih = 0; ih < 4; ++ih)
      #pragma unroll
      for (int ct = 0; ct < 4; ++ct) {
        acc[0][ct] = __builtin_amdgcn_mfma_f32_16x16x32_bf16(hA[ih][0], Bf[2 + ih][ct], acc[0][ct], 0, 0, 0);
        acc[1][ct] = __builtin_amdgcn_mfma_f32_16x16x32_bf16(hA[ih][1], Bf[2 + ih][ct], acc[1][ct], 0, 0, 0);
      }

    // ---- partials -> LDS (b128). C/D: col=lane&15, row=(lane>>4)*4+j ----
    #pragma unroll
    for (int rt = 0; rt < 2; ++rt)
      #pragma unroll
      for (int ct = 0; ct < 4; ++ct)
        *reinterpret_cast<float4*>(&gbuf[kw][ct * 16 + l15][rt * 16 + kg * 4]) =
            *reinterpret_cast<float4*>(&acc[rt][ct]);
    __syncthreads();

    // ---- cell update ----
    float gs[4];
    #pragma unroll
    for (int g = 0; g < 4; ++g) {
      float s = bsum[g];
      #pragma unroll
      for (int k2 = 0; k2 < 8; ++k2) s += gbuf[k2][g * 16 + uu][b_l];
      gs[g] = s;
    }
    const float ig = sigm(gs[0]);
    const float fg = sigm(gs[1]);
    const float gg = tanh_s(gs[2]);
    const float og = sigm(gs[3]);
    c_state = fg * c_state + ig * gg;
    const float h = og * tanh_s(c_state);

    orow[(size_t)t * U_SZ] = h;                       // fp32 out (plain, L2)
    store_b16_bypass(hdst + hidx, (u32)f2bf(h));      // bf16 h -> L3

    // ---- publish: every thread drains own stores, then one flag ----
    asm volatile("s_waitcnt vmcnt(0)" ::: "memory");
    __syncthreads();                                  // also WAR-protects gbuf
    if (tid == 0)
      __hip_atomic_store(flags + wg, (u32)(t + 1), __ATOMIC_RELAXED, __HIP_MEMORY_SCOPE_AGENT);
  }
}

// ---- launch ---------------------------------------------------------------
extern "C" void kernel_launch(void* const* d_in, const int* in_sizes, int n_in,
                              void* d_out, int out_size, void* d_ws, size_t ws_size,
                              hipStream_t stream) {
  const float* X   = (const float*)d_in[0];
  const float* Wih = (const float*)d_in[1];
  const float* Whh = (const float*)d_in[2];
  const float* bih = (const float*)d_in[3];
  const float* bhh = (const float*)d_in[4];
  float* out = (float*)d_out;
  char*  ws  = (char*)d_ws;

  u16* Xb    = (u16*)(ws + XB_OFF);
  u16* Wc    = (u16*)(ws + WC_OFF);
  u32* flags = (u32*)(ws + FLAG_OFF);
  u16* hbuf  = (u16*)(ws + HBUF_OFF);

  hipLaunchKernelGGL(k_convX, dim3(32768), dim3(256), 0, stream, X, Xb);
  hipLaunchKernelGGL(k_packW, dim3(4096), dim3(256), 0, stream, Wih, Whh, Wc);
  hipLaunchKernelGGL(k_zero,  dim3(513),  dim3(256), 0, stream, (u32*)hbuf, flags);

  void* args[] = {(void*)&Xb, (void*)&Wc, (void*)&bih, (void*)&bhh,
                  (void*)&hbuf, (void*)&flags, (void*)&out};
  hipLaunchCooperativeKernel((void*)lstm_scan, dim3(256), dim3(512), args, 0, stream);
}